// Round 12
// baseline (157.586 us; speedup 1.0000x reference)
//
#include <hip/hip_runtime.h>

#define BATCH   16384
#define NUM_NUM 32
#define NUM_CAT 32
#define CARD    128
#define OUT_F   32
#define XSTRIDE 4128   // NUM_NUM + NUM_CAT*CARD
#define OSTRIDE 1056   // NUM_NUM + NUM_CAT*OUT_F

#define TRB 64   // rows per block

typedef const __attribute__((address_space(1))) void* as1_cvp;
typedef __attribute__((address_space(3))) void*       as3_vp;

// Block = (feature-PAIR p, 64-row stripe). 256 thr = 4 waves; wave og owns outs
// [og*8,+8) of each feature (W/bias wave-uniform s_load, SMEM pipe); lane = row.
// Pair layout: x cols [NUM_NUM + p*256, +256) -> chunk ck = 64 consecutive floats
// -> staged segments are 256B CONTIGUOUS per row (vs r11's 128B; the 3.9 TB/s
// granule ceiling is the target). Chunks 0,1 = feature 2p cols 0-63/64-127;
// chunks 2,3 = feature 2p+1. r11's proven dbuf order: [compute k][sync][stage k+2].
// Buffer swizzle (16-quad rows): logical Q = row*16 + q, phys = Q ^ ((Q>>4)&7)
// (involution; XOR bits 0-2 only). Read (fixed h,k): addr l*16 + h*8 + (k^(l&7))
// -> ~2-way nominal. Stage instr i: lane l -> row i*4+(l>>4), q (l&15)^(row&7):
// 16-lane groups cover one row's 256B permuted -> 4 full 64B lines per segment.
// Joint epilogue: ctr (64x16 quads, 16KB) OVERLAYS buf0 (dead after compute(2)
// +sync); pair's 64 out floats are row-contiguous -> each thread stores a full
// 64B line. LDS total 32KB -> 5 blocks/CU = 20 waves (r11 TLP preserved).
__global__ __launch_bounds__(256, 5) void emb_pair(const float* __restrict__ x,
                                                   const float* __restrict__ Wm,
                                                   const float* __restrict__ bias,
                                                   float* __restrict__ out) {
    __shared__ float4 xs[2][1024];  // 2 x 16 KB; xs[0] doubles as ctr in epilogue

    const int p    = blockIdx.x;          // feature pair 0..15
    const int row0 = blockIdx.y * TRB;
    const int tid  = threadIdx.x;
    const int l    = tid & 63;
    const int lx   = l & 7;
    const int og   = __builtin_amdgcn_readfirstlane(tid >> 6);  // wave out-group

    const float* xg = x + (size_t)row0 * XSTRIDE + NUM_NUM + p * 256;

    // stage source offsets: instr i = og*4+s covers phys quads [i*64,+64)
    int soff[4];
#pragma unroll
    for (int s = 0; s < 4; ++s) {
        const int i  = og * 4 + s;
        const int sr = i * 4 + (l >> 4);          // row
        const int sq = (l & 15) ^ (sr & 7);       // inverse-swizzled col-quad
        soff[s] = sr * XSTRIDE + sq * 4;
    }

    auto stage = [&](int ck, int buf) {
#pragma unroll
        for (int s = 0; s < 4; ++s)
            __builtin_amdgcn_global_load_lds((as1_cvp)(xg + ck * 64 + soff[s]),
                                             (as3_vp)&xs[buf][(og * 4 + s) * 64 + l],
                                             16, 0, 0);
    };

    float acc[2][8];
#pragma unroll
    for (int a = 0; a < 2; ++a)
#pragma unroll
        for (int k = 0; k < 8; ++k) acc[a][k] = 0.0f;

    stage(0, 0);
    stage(1, 1);
    __syncthreads();  // cold-start drain (once per block)

    // compute one 64-col chunk from xb into acc[fs] (feature 2p+fs, col base cb)
    auto compute = [&](const float4* xb, int fs, int cb) {
        const float4* wqf = (const float4*)Wm +
                            ((size_t)(p * 2 + fs) * (CARD * OUT_F / 4) + og * 2);
        float* a = acc[fs];
#pragma unroll
        for (int h = 0; h < 2; ++h) {
            float4 xv[8];
#pragma unroll
            for (int k = 0; k < 8; ++k) xv[k] = xb[l * 16 + h * 8 + (k ^ lx)];
#pragma unroll
            for (int k = 0; k < 8; ++k) {
#pragma unroll
                for (int cc = 0; cc < 4; ++cc) {
                    const int    c  = cb + h * 32 + k * 4 + cc;
                    const float4 wa = wqf[c * 8];      // s_load (wave-uniform)
                    const float4 wb = wqf[c * 8 + 1];
                    const float  xf = (&xv[k].x)[cc];
                    a[0] += xf * wa.x;  a[1] += xf * wa.y;
                    a[2] += xf * wa.z;  a[3] += xf * wa.w;
                    a[4] += xf * wb.x;  a[5] += xf * wb.y;
                    a[6] += xf * wb.z;  a[7] += xf * wb.w;
                }
            }
        }
    };

    compute(xs[0], 0, 0);
    __syncthreads();          // buf0 readers done
    stage(2, 0);
    compute(xs[1], 0, 64);
    __syncthreads();          // publishes stage(2) [issued one compute earlier]; buf1 free
    stage(3, 1);
    compute(xs[0], 1, 0);
    __syncthreads();          // publishes stage(3); buf0 readers done -> ctr overlay safe
    compute(xs[1], 1, 64);

    // ---- joint epilogue through ctr = xs[0]: 64 rows x 16 quads, swz q^(r&7) ----
    float4* ctr = xs[0];
#pragma unroll
    for (int fs = 0; fs < 2; ++fs) {
        const float4 b0 = ((const float4*)bias)[(p * 2 + fs) * 8 + og * 2];
        const float4 b1 = ((const float4*)bias)[(p * 2 + fs) * 8 + og * 2 + 1];
        const int    q0 = fs * 8 + og * 2;
        ctr[l * 16 + (q0 ^ lx)] =
            make_float4(acc[fs][0] + b0.x, acc[fs][1] + b0.y,
                        acc[fs][2] + b0.z, acc[fs][3] + b0.w);
        ctr[l * 16 + ((q0 + 1) ^ lx)] =
            make_float4(acc[fs][4] + b1.x, acc[fs][5] + b1.y,
                        acc[fs][6] + b1.z, acc[fs][7] + b1.w);
    }
    asm volatile("s_waitcnt lgkmcnt(0)" ::: "memory");  // own ds_writes done
    __builtin_amdgcn_s_barrier();                        // raw: vmcnt NOT drained

    {
        const int r  = tid >> 2;          // 4 threads per row
        const int q0 = (tid & 3) * 4;     // 4 quads = one full 64B line per thread
        float4 v[4];
#pragma unroll
        for (int j = 0; j < 4; ++j) v[j] = ctr[r * 16 + ((q0 + j) ^ (r & 7))];
        float* orow = out + (size_t)(row0 + r) * OSTRIDE + NUM_NUM + p * 64 + q0 * 4;
#pragma unroll
        for (int j = 0; j < 4; ++j) *(float4*)(orow + j * 4) = v[j];
    }

    // ---- numeric passthrough: p==0 blocks copy their stripe's first 32 cols ----
    if (p == 0) {
#pragma unroll
        for (int it = 0; it < 2; ++it) {
            const int idx = it * 256 + tid;  // 512 float4
            const int r   = idx >> 3;
            const int c4  = (idx & 7) << 2;
            *(float4*)(out + (size_t)(row0 + r) * OSTRIDE + c4) =
                *(const float4*)(x + (size_t)(row0 + r) * XSTRIDE + c4);
        }
    }
}

extern "C" void kernel_launch(void* const* d_in, const int* in_sizes, int n_in,
                              void* d_out, int out_size, void* d_ws, size_t ws_size,
                              hipStream_t stream) {
    const float* x    = (const float*)d_in[0];
    const float* W    = (const float*)d_in[1];
    const float* bias = (const float*)d_in[2];
    float*       out  = (float*)d_out;

    dim3 grid(NUM_CAT / 2, BATCH / TRB);  // (16, 256), pair fastest
    emb_pair<<<grid, 256, 0, stream>>>(x, W, bias, out);
}

// Round 13
// 84.962 us; speedup vs baseline: 1.8548x; 1.8548x over previous
//
#include <hip/hip_runtime.h>

#define BATCH   16384
#define NUM_NUM 32
#define NUM_CAT 32
#define CARD    128
#define OUT_F   32
#define XSTRIDE 4128   // NUM_NUM + NUM_CAT*CARD
#define OSTRIDE 1056   // NUM_NUM + NUM_CAT*OUT_F

#define TRB    64              // rows per block
#define CK     32              // K cols per chunk
#define NCHUNK (CARD / CK)     // 4
#define QPB    (TRB * CK / 4)  // 512 quads per buffer (8 KB)

typedef const __attribute__((address_space(1))) void* as1_cvp;
typedef __attribute__((address_space(3))) void*       as3_vp;

// r11 structure (proven 87.5us) with 8 blocks/CU. 256 thr = 4 waves; wave og
// owns outs [og*8,+8) -> W/bias wave-uniform s_load (SMEM pipe). Lane = row.
// Dbuf order: [compute k][sync][stage k+2] (stage drained by a sync one full
// compute later). launch_bounds(256,8): VGPR cap 64; live set kept ~45-55 BY
// CONSTRUCTION (xv[4] halves, straight-line code, no lambdas/runtime-indexed
// register arrays - r8/r12 codegen lessons) -> no spill, no forced serialization.
// 8 blocks x 4 waves = 32 waves/CU to cover lgkm-mix stalls + barrier drains.
// Swizzles identical to r11 (read ~1.33x bank cost accepted; stage 128B segs).
__global__ __launch_bounds__(256, 8) void emb_gemv(const float* __restrict__ x,
                                                   const float* __restrict__ Wm,
                                                   const float* __restrict__ bias,
                                                   float* __restrict__ out) {
    __shared__ float4 lds[2 * QPB];  // 16 KB: buf0=[0,512), buf1=[512,1024); ctr=buf0

    const int f    = blockIdx.x;
    const int row0 = blockIdx.y * TRB;
    const int tid  = threadIdx.x;
    const int l    = tid & 63;
    const int lx   = l & 7;
    const int og   = __builtin_amdgcn_readfirstlane(tid >> 6);  // wave out-group

    const float* xg   = x + (size_t)row0 * XSTRIDE + NUM_NUM + f * CARD;
    const int    srow = l >> 3;                    // stage: row-within-8
    const int    scq  = (l & 7) ^ ((l >> 3) & 7);  // stage: inverse-swizzled col-quad

    // stage chunk ck -> buffer buf: 8 gload_lds block-wide (2 per wave)
#define STAGE(ck, buf)                                                                   \
    {                                                                                    \
        _Pragma("unroll") for (int s = 0; s < 2; ++s) {                                  \
            const int i = og * 2 + s;                                                    \
            __builtin_amdgcn_global_load_lds(                                            \
                (as1_cvp)(xg + (size_t)(i * 8 + srow) * XSTRIDE + (ck) * CK + scq * 4),  \
                (as3_vp)&lds[(buf) * QPB + i * 64 + l], 16, 0, 0);                       \
        }                                                                                \
    }

    STAGE(0, 0);
    STAGE(1, 1);

    // wave-uniform W quad pointer: wq[c*8], wq[c*8+1] = W[f][c][og*8 .. +8)
    const float4* __restrict__ wq =
        (const float4*)Wm + ((size_t)f * (CARD * OUT_F / 4) + og * 2);

    float acc[8];
#pragma unroll
    for (int k = 0; k < 8; ++k) acc[k] = 0.0f;

    __syncthreads();  // cold-start drain (once per block)

    for (int ck = 0; ck < NCHUNK; ++ck) {
        const float4* xb = &lds[(ck & 1) * QPB];

#pragma unroll
        for (int h = 0; h < 2; ++h) {
            float4 xv[4];
#pragma unroll
            for (int c4 = 0; c4 < 4; ++c4) xv[c4] = xb[l * 8 + ((h * 4 + c4) ^ lx)];

#pragma unroll
            for (int c4 = 0; c4 < 4; ++c4) {
#pragma unroll
                for (int cc = 0; cc < 4; ++cc) {
                    const int    c  = ck * CK + (h * 4 + c4) * 4 + cc;
                    const float4 wa = wq[c * 8];      // s_load_dwordx4 (uniform)
                    const float4 wb = wq[c * 8 + 1];
                    const float  xf = (&xv[c4].x)[cc];
                    acc[0] += xf * wa.x;  acc[1] += xf * wa.y;
                    acc[2] += xf * wa.z;  acc[3] += xf * wa.w;
                    acc[4] += xf * wb.x;  acc[5] += xf * wb.y;
                    acc[6] += xf * wb.z;  acc[7] += xf * wb.w;
                }
            }
        }

        if (ck < NCHUNK - 1) {
            __syncthreads();                  // publishes stage(ck+1); frees buf ck&1
            if (ck + 2 < NCHUNK) STAGE(ck + 2, ck & 1);
        }
    }

    // ---- epilogue: bias (uniform) + transpose through ctr (= buf0, dead region) ----
    const float4 b0 = ((const float4*)bias)[f * 8 + og * 2];
    const float4 b1 = ((const float4*)bias)[f * 8 + og * 2 + 1];
    lds[l * 8 + ((og * 2) ^ lx)] =
        make_float4(acc[0] + b0.x, acc[1] + b0.y, acc[2] + b0.z, acc[3] + b0.w);
    lds[l * 8 + ((og * 2 + 1) ^ lx)] =
        make_float4(acc[4] + b1.x, acc[5] + b1.y, acc[6] + b1.z, acc[7] + b1.w);
    __syncthreads();

    // coalesced stores: 4 threads cover one row's 128B
    {
        const int    r  = tid >> 2;
        const int    qp = (tid & 3) * 2;
        const float4 v0 = lds[r * 8 + (qp ^ (r & 7))];
        const float4 v1 = lds[r * 8 + ((qp + 1) ^ (r & 7))];
        float* orow = out + (size_t)(row0 + r) * OSTRIDE + NUM_NUM + f * OUT_F + qp * 4;
        *(float4*)(orow)     = v0;
        *(float4*)(orow + 4) = v1;
    }

    // ---- numeric passthrough: distributed across f = (stripe & 31) ----
    if (f == (blockIdx.y & 31)) {
#pragma unroll
        for (int it = 0; it < 2; ++it) {
            const int idx = it * 256 + tid;  // 512 float4
            const int r   = idx >> 3;
            const int c4  = (idx & 7) << 2;
            *(float4*)(out + (size_t)(row0 + r) * OSTRIDE + c4) =
                *(const float4*)(x + (size_t)(row0 + r) * XSTRIDE + c4);
        }
    }
#undef STAGE
}

extern "C" void kernel_launch(void* const* d_in, const int* in_sizes, int n_in,
                              void* d_out, int out_size, void* d_ws, size_t ws_size,
                              hipStream_t stream) {
    const float* x    = (const float*)d_in[0];
    const float* W    = (const float*)d_in[1];
    const float* bias = (const float*)d_in[2];
    float*       out  = (float*)d_out;

    dim3 grid(NUM_CAT, BATCH / TRB);  // (32, 256), f fastest
    emb_gemv<<<grid, 256, 0, stream>>>(x, W, bias, out);
}